// Round 2
// baseline (196.353 us; speedup 1.0000x reference)
//
#include <hip/hip_runtime.h>
#include <stdint.h>

// Problem constants
#define B_   16
#define D_   256
#define T_   4096
#define K_   1024
#define N_   (B_ * T_)      // 65536 points
#define BM   64             // points per block (R6: revert to R0 structure)

typedef __attribute__((ext_vector_type(4))) float floatx4;
typedef __attribute__((ext_vector_type(2))) float floatx2;
typedef __attribute__((ext_vector_type(2))) long longx2;

// ---- Kernel 0: emb fp32 -> fp8 e4m3 (scaled x1024), stored in PIECE order:
// tile ct = codes [ct*16, ct*16+16), 4 KB = 4 pieces of 1 KB. Byte for
// (code c, dim d): ct=c>>4, ml=c&15, kk=d>>5, quad=(d>>3)&3, b=d&7 at
//   ct*4096 + (kk>>1)*1024 + (quad*16+ml)*16 + (kk&1)*8 + b
// -> k-loop lane L=(quad*16+ml) reads piece i at ct*4096+i*1024+L*16: each
// load covers 1 KB contiguous across the wave and lands directly in MFMA
// B-fragment registers. esqh[c] = 1024*0.5*||e_exact||^2. Also zeroes loss.
__global__ __launch_bounds__(256) void emb_prep(const float* __restrict__ emb,
                                                uint32_t* __restrict__ embf8,
                                                float* __restrict__ esqh,
                                                float* __restrict__ lossp) {
    int w = threadIdx.x >> 6, lane = threadIdx.x & 63;
    int k = blockIdx.x * 4 + w;                       // one wave per code row
    float4 v = ((const float4*)emb)[k * 64 + lane];   // d0 = lane*4
    float a0 = v.x * 1024.f, a1 = v.y * 1024.f, a2 = v.z * 1024.f, a3 = v.w * 1024.f;
    int p = __builtin_amdgcn_cvt_pk_fp8_f32(a0, a1, 0, false);
    p = __builtin_amdgcn_cvt_pk_fp8_f32(a2, a3, p, true);
    int kk = lane >> 3, quad = (lane >> 1) & 3;       // from d0 = lane*4
    int widx = (k >> 4) * 1024 + (kk >> 1) * 256 + (quad * 16 + (k & 15)) * 4
             + (kk & 1) * 2 + (lane & 1);
    embf8[widx] = (uint32_t)p;
    float ss = a0 * a0 + a1 * a1 + a2 * a2 + a3 * a3;   // exact (pre-fp8) scaled norm
    #pragma unroll
    for (int off = 32; off; off >>= 1) ss += __shfl_xor(ss, off, 64);
    if (lane == 0) esqh[k] = ss * (0.5f / 1024.f);      // = 1024 * 0.5*||e||^2
    if (blockIdx.x == 0 && threadIdx.x == 0) *lossp = 0.f;
}

// ---- Main kernel (R6: R0 structure + software-pipelined k-loop) ----
// 256 threads / 4 waves, BM=64. Wave w owns ALL 64 points (4 A-sets,
// 32 MFMA/tile, 4 independent acc chains) x code quarter [w*16, w*16+16)
// tiles. Zero barriers in the k-loop.
// R6 changes vs R0 (theory: k-loop latency-serialized, VGPR=76 proved the
// compiler was reloading afr from LDS + consuming qq loads same-iteration):
//  - qqA/qqB register double-buffer: tile j+1's 4 global loads issue
//    before tile j's 32 MFMAs -> counted vmcnt, L2 latency hidden.
//  - first tile prefetched before the barrier.
//  - esqh staged to LDS at P1; per-iter eh is a ds_read issued ahead of
//    the MFMA block (hidden), not a per-iter global load.
//  - launch_bounds(256,4): VGPR cap 128 = exactly the bracket that keeps
//    the grid's 4 blocks/CU resident while allowing afr(64)+qq(32) live.
//  - P1 unroll 4 for deeper MLP against L3 latency.
// xs swizzle (phases 1-3), byte offset of d in row t:
//   c=d>>4, h=(d>>3)&1 -> ((c ^ (t&15))<<4) + ((h ^ ((t>>4)&1))<<3) + (d&7)
// Phase 4 reuses xs with a 16B-chunk swizzle: chunk g at ((g ^ (t&15))<<4).
// Argmin state: packed float, low 10 mantissa bits = code index; v_min_f32
// compares true value to 2^-13 relative, index rides along.
__global__ __launch_bounds__(256, 4) void vq_main(const float* __restrict__ z,
                                                  const uint32_t* __restrict__ embf8,
                                                  const float* __restrict__ esqh,
                                                  float* __restrict__ out0,
                                                  float* __restrict__ lossp) {
    __shared__ __align__(16) unsigned char xs[BM * 256];   // 16 KiB
    __shared__ float esq_lds[K_];                          // 4 KiB
    __shared__ float wvals[4][BM];
    __shared__ int   pidx[BM];
    __shared__ float zred[4];

    int tid  = threadIdx.x;
    int lane = tid & 63, w = tid >> 6;
    int ml   = lane & 15, quad = lane >> 4;
    int blk  = blockIdx.x;
    int b    = blk >> 6;
    int t0   = (blk & 63) * BM;
    const float* zb = z + (size_t)b * (D_ * T_) + t0;

    // stage esqh -> LDS (one float4 per thread, 4 KB)
    ((float4*)esq_lds)[tid] = ((const float4*)esqh)[tid];

    // ---- Phase 1: load z [d][t], fp8-convert, transposed+swizzled store; Sum z^2 ----
    float zsq = 0.f;
    {
        int t = lane, hf = (t >> 4) & 1;
        #pragma unroll 4
        for (int j = 0; j < 8; ++j) {
            int dgrp = w + 4 * j;
            int d0 = dgrp * 8;
            float f0 = zb[(d0 + 0) * T_ + t];
            float f1 = zb[(d0 + 1) * T_ + t];
            float f2 = zb[(d0 + 2) * T_ + t];
            float f3 = zb[(d0 + 3) * T_ + t];
            float f4 = zb[(d0 + 4) * T_ + t];
            float f5 = zb[(d0 + 5) * T_ + t];
            float f6 = zb[(d0 + 6) * T_ + t];
            float f7 = zb[(d0 + 7) * T_ + t];
            zsq += f0*f0 + f1*f1 + f2*f2 + f3*f3 + f4*f4 + f5*f5 + f6*f6 + f7*f7;
            uint32_t p0 = (uint32_t)__builtin_amdgcn_cvt_pk_fp8_f32(f0, f1, 0, false);
            p0 = (uint32_t)__builtin_amdgcn_cvt_pk_fp8_f32(f2, f3, (int)p0, true);
            uint32_t p1 = (uint32_t)__builtin_amdgcn_cvt_pk_fp8_f32(f4, f5, 0, false);
            p1 = (uint32_t)__builtin_amdgcn_cvt_pk_fp8_f32(f6, f7, (int)p1, true);
            int c = dgrp >> 1, h = dgrp & 1;
            *(uint2*)&xs[t * 256 + ((c ^ (t & 15)) << 4) + ((h ^ hf) << 3)] =
                make_uint2(p0, p1);
        }
    }

    // ---- prefetch tile j=0 B-fragments (independent of xs; hides under barrier) ----
    int ct0 = w * 16;
    const char* ebL = (const char*)embf8 + (size_t)ct0 * 4096 + (size_t)lane * 16;
    longx2 qqA[4], qqB[4];
    #pragma unroll
    for (int i = 0; i < 4; ++i)
        qqA[i] = *(const longx2*)(ebL + i * 1024);

    __syncthreads();

    // ---- Phase 2: persistent A fragments, ALL 4 point-sets per wave ----
    long afr[4][8];
    #pragma unroll
    for (int s = 0; s < 4; ++s) {
        int pnt = s * 16 + ml;
        #pragma unroll
        for (int kk = 0; kk < 8; ++kk) {
            int c = 2 * kk + (quad >> 1), h = quad & 1;
            afr[s][kk] = *(const long*)&xs[pnt * 256 + ((c ^ ml) << 4) + ((h ^ (s & 1)) << 3)];
        }
    }

    float bv[4][4];
    #pragma unroll
    for (int s = 0; s < 4; ++s)
        #pragma unroll
        for (int i = 0; i < 4; ++i) bv[s][i] = 1e30f;

    // ---- Phase 3: barrier-free pipelined k-loop ----
    const unsigned hi_mask = 0xFFFFFC00u;
    auto STEP = [&](const longx2* qq, int j) {
        float eh = esq_lds[(ct0 + j) * 16 + ml];   // ds_read, hidden under MFMAs
        floatx4 a0 = {0.f,0.f,0.f,0.f}, a1 = {0.f,0.f,0.f,0.f};
        floatx4 a2 = {0.f,0.f,0.f,0.f}, a3 = {0.f,0.f,0.f,0.f};
        #pragma unroll
        for (int i = 0; i < 4; ++i) {
            long bf0 = qq[i][0], bf1 = qq[i][1];   // frags kk=2i, 2i+1
            a0 = __builtin_amdgcn_mfma_f32_16x16x32_fp8_fp8(afr[0][2*i],     bf0, a0, 0, 0, 0);
            a1 = __builtin_amdgcn_mfma_f32_16x16x32_fp8_fp8(afr[1][2*i],     bf0, a1, 0, 0, 0);
            a2 = __builtin_amdgcn_mfma_f32_16x16x32_fp8_fp8(afr[2][2*i],     bf0, a2, 0, 0, 0);
            a3 = __builtin_amdgcn_mfma_f32_16x16x32_fp8_fp8(afr[3][2*i],     bf0, a3, 0, 0, 0);
            a0 = __builtin_amdgcn_mfma_f32_16x16x32_fp8_fp8(afr[0][2*i + 1], bf1, a0, 0, 0, 0);
            a1 = __builtin_amdgcn_mfma_f32_16x16x32_fp8_fp8(afr[1][2*i + 1], bf1, a1, 0, 0, 0);
            a2 = __builtin_amdgcn_mfma_f32_16x16x32_fp8_fp8(afr[2][2*i + 1], bf1, a2, 0, 0, 0);
            a3 = __builtin_amdgcn_mfma_f32_16x16x32_fp8_fp8(afr[3][2*i + 1], bf1, a3, 0, 0, 0);
        }
        // packed key = bits(1024*(0.5||e||^2 - x.e)) with low 10 bits = code
        unsigned cbits = (unsigned)((ct0 + j) * 16 + ml);
        #pragma unroll
        for (int i = 0; i < 4; ++i) {
            float d0 = eh - a0[i];
            bv[0][i] = fminf(bv[0][i], __uint_as_float((__float_as_uint(d0) & hi_mask) | cbits));
            float d1 = eh - a1[i];
            bv[1][i] = fminf(bv[1][i], __uint_as_float((__float_as_uint(d1) & hi_mask) | cbits));
            float d2 = eh - a2[i];
            bv[2][i] = fminf(bv[2][i], __uint_as_float((__float_as_uint(d2) & hi_mask) | cbits));
            float d3 = eh - a3[i];
            bv[3][i] = fminf(bv[3][i], __uint_as_float((__float_as_uint(d3) & hi_mask) | cbits));
        }
    };

    #pragma unroll 1
    for (int j = 0; j < 16; j += 2) {
        // prefetch tile j+1 while computing tile j
        #pragma unroll
        for (int i = 0; i < 4; ++i)
            qqB[i] = *(const longx2*)(ebL + (size_t)(j + 1) * 4096 + i * 1024);
        STEP(qqA, j);
        if (j + 2 < 16) {
            #pragma unroll
            for (int i = 0; i < 4; ++i)
                qqA[i] = *(const longx2*)(ebL + (size_t)(j + 2) * 4096 + i * 1024);
        }
        STEP(qqB, j + 1);
    }

    // ---- per-wave min over the 16 code-lanes; publish packed candidates ----
    #pragma unroll
    for (int s = 0; s < 4; ++s)
        #pragma unroll
        for (int i = 0; i < 4; ++i) {
            float v = bv[s][i];
            #pragma unroll
            for (int off = 1; off < 16; off <<= 1)
                v = fminf(v, __shfl_xor(v, off, 64));
            if (ml == 0) wvals[w][s * 16 + quad * 4 + i] = v;
        }
    #pragma unroll
    for (int off = 32; off; off >>= 1) zsq += __shfl_xor(zsq, off, 64);
    if (lane == 0) zred[w] = zsq;
    __syncthreads();

    // ---- cross-wave merge (wave 0) + loss via algebra ----
    if (tid < 64) {
        int t = tid;
        float wv = fminf(fminf(wvals[0][t], wvals[1][t]),
                         fminf(wvals[2][t], wvals[3][t]));
        pidx[t] = (int)(__float_as_uint(wv) & 1023u);
        float lsum = wv;          // packed float == bv to 2^-13 relative
        #pragma unroll
        for (int off = 32; off; off >>= 1) lsum += __shfl_xor(lsum, off, 64);
        if (t == 0) {
            float tot = zred[0] + zred[1] + zred[2] + zred[3] + lsum * (2.0f / 1024.f);
            atomicAdd(lossp, tot * (1.25f / 16777216.0f));   // 1.25/(N*D)
        }
    }
    __syncthreads();

    // ---- Phase 4a: gather winning fp8 rows into xs (piece layout) ----
    #pragma unroll
    for (int m = 0; m < 4; ++m) {
        int t = (tid >> 4) + 16 * m;
        int g = tid & 15;             // chunk: piece i=g>>2, q=g&3
        int code = pidx[t];
        const char* src = (const char*)embf8 + (size_t)(code >> 4) * 4096
                        + (g >> 2) * 1024 + ((g & 3) * 16 + (code & 15)) * 16;
        uint4 v = *(const uint4*)src;
        *(uint4*)&xs[t * 256 + ((g ^ (t & 15)) << 4)] = v;
    }
    __syncthreads();

    // ---- Phase 4b: dequant + transpose-write (piece-order byte decode) ----
    float* ob = out0 + (size_t)b * (D_ * T_) + t0;
    {
        int t = lane;
        #pragma unroll
        for (int jj = 0; jj < 4; ++jj) {
            int g = w + 4 * jj;            // 16-byte chunk 0..15
            uint4 v = *(const uint4*)&xs[t * 256 + ((g ^ (t & 15)) << 4)];
            uint32_t wd[4] = {v.x, v.y, v.z, v.w};
            #pragma unroll
            for (int u = 0; u < 4; ++u) {
                int kk = (g >> 2) * 2 + (u >> 1);
                int d0 = kk * 32 + (g & 3) * 8 + (u & 1) * 4;
                floatx2 lo = __builtin_amdgcn_cvt_pk_f32_fp8((int)wd[u], false);
                floatx2 hi = __builtin_amdgcn_cvt_pk_f32_fp8((int)wd[u], true);
                ob[(d0 + 0) * T_ + t] = lo[0] * (1.f / 1024.f);
                ob[(d0 + 1) * T_ + t] = lo[1] * (1.f / 1024.f);
                ob[(d0 + 2) * T_ + t] = hi[0] * (1.f / 1024.f);
                ob[(d0 + 3) * T_ + t] = hi[1] * (1.f / 1024.f);
            }
        }
    }
}

extern "C" void kernel_launch(void* const* d_in, const int* in_sizes, int n_in,
                              void* d_out, int out_size, void* d_ws, size_t ws_size,
                              hipStream_t stream) {
    (void)in_sizes; (void)n_in; (void)out_size; (void)ws_size;
    const float* z   = (const float*)d_in[0];
    const float* emb = (const float*)d_in[1];

    uint32_t* embf8 = (uint32_t*)d_ws;                              // 256 KiB
    float*    esqh  = (float*)((char*)d_ws + (size_t)K_ * D_);      // 4 KiB

    float* out0  = (float*)d_out;
    float* lossp = out0 + (size_t)N_ * D_;

    emb_prep<<<K_ / 4, 256, 0, stream>>>(emb, embf8, esqh, lossp);
    vq_main<<<N_ / BM, 256, 0, stream>>>(z, embf8, esqh, out0, lossp);
}

// Round 3
// 138.734 us; speedup vs baseline: 1.4153x; 1.4153x over previous
//
#include <hip/hip_runtime.h>
#include <stdint.h>

// Problem constants
#define B_   16
#define D_   256
#define T_   4096
#define K_   1024
#define N_   (B_ * T_)      // 65536 points
#define BM   64             // points per block

typedef __attribute__((ext_vector_type(4))) float floatx4;
typedef __attribute__((ext_vector_type(2))) float floatx2;
typedef __attribute__((ext_vector_type(2))) long longx2;

// ---- Kernel 0: emb fp32 -> fp8 e4m3 (scaled x1024), stored in PIECE order:
// tile ct = codes [ct*16, ct*16+16), 4 KB = 4 pieces of 1 KB. Byte for
// (code c, dim d): ct=c>>4, ml=c&15, kk=d>>5, quad=(d>>3)&3, b=d&7 at
//   ct*4096 + (kk>>1)*1024 + (quad*16+ml)*16 + (kk&1)*8 + b
// -> k-loop lane L=(quad*16+ml) reads piece i at ct*4096+i*1024+L*16: each
// load covers 1 KB contiguous across the wave and lands directly in MFMA
// B-fragment registers. esqh[c] = 1024*0.5*||e_exact||^2. Also zeroes loss.
__global__ __launch_bounds__(256) void emb_prep(const float* __restrict__ emb,
                                                uint32_t* __restrict__ embf8,
                                                float* __restrict__ esqh,
                                                float* __restrict__ lossp) {
    int w = threadIdx.x >> 6, lane = threadIdx.x & 63;
    int k = blockIdx.x * 4 + w;                       // one wave per code row
    float4 v = ((const float4*)emb)[k * 64 + lane];   // d0 = lane*4
    float a0 = v.x * 1024.f, a1 = v.y * 1024.f, a2 = v.z * 1024.f, a3 = v.w * 1024.f;
    int p = __builtin_amdgcn_cvt_pk_fp8_f32(a0, a1, 0, false);
    p = __builtin_amdgcn_cvt_pk_fp8_f32(a2, a3, p, true);
    int kk = lane >> 3, quad = (lane >> 1) & 3;       // from d0 = lane*4
    int widx = (k >> 4) * 1024 + (kk >> 1) * 256 + (quad * 16 + (k & 15)) * 4
             + (kk & 1) * 2 + (lane & 1);
    embf8[widx] = (uint32_t)p;
    float ss = a0 * a0 + a1 * a1 + a2 * a2 + a3 * a3;   // exact (pre-fp8) scaled norm
    #pragma unroll
    for (int off = 32; off; off >>= 1) ss += __shfl_xor(ss, off, 64);
    if (lane == 0) esqh[k] = ss * (0.5f / 1024.f);      // = 1024 * 0.5*||e||^2
    if (blockIdx.x == 0 && threadIdx.x == 0) *lossp = 0.f;
}

// ---- Main kernel (R7 = R0 + k-loop register double-buffer, NOTHING else) ----
// xs swizzle (phases 1-3), byte offset of d in row t:
//   c=d>>4, h=(d>>3)&1 -> ((c ^ (t&15))<<4) + ((h ^ ((t>>4)&1))<<3) + (d&7)
// Phase 4 reuses xs with a 16B-chunk swizzle: chunk g at ((g ^ (t&15))<<4).
// Wave w owns ALL 64 points (4 A-sets, 32 MFMA/tile) x code quarter
// [w*16, w*16+16) tiles. Zero barriers in the k-loop.
// Argmin state is ONE packed float per acc element: low 10 mantissa bits
// replaced by the code index (K=1024); v_min_f32 compares true value to
// 2^-13 relative, index rides along. Ties -> allowed argmin flips.
// Register budget (R2 lesson: rocprof VGPR_Count is ARCH regs only; afr's
// 64 live in AGPRs, combined pool is what launch_bounds caps): R0 ran at
// ~76 arch + 64 acc = 140 combined under the (256,3) cap of ~170.
// R7 adds qqB(16) + ehA/ehB(2) -> ~158 combined: still under cap, NO spill.
// (256,4) in R2 capped combined at 128 -> 40 MB scratch traffic; never again.
__global__ __launch_bounds__(256, 3) void vq_main(const float* __restrict__ z,
                                                  const uint32_t* __restrict__ embf8,
                                                  const float* __restrict__ esqh,
                                                  float* __restrict__ out0,
                                                  float* __restrict__ lossp) {
    __shared__ __align__(16) unsigned char xs[BM * 256];   // 16 KiB
    __shared__ float wvals[4][BM];
    __shared__ int   pidx[BM];
    __shared__ float zred[4];

    int tid  = threadIdx.x;
    int lane = tid & 63, w = tid >> 6;
    int ml   = lane & 15, quad = lane >> 4;
    int blk  = blockIdx.x;
    int b    = blk >> 6;
    int t0   = (blk & 63) * BM;
    const float* zb = z + (size_t)b * (D_ * T_) + t0;

    // ---- Phase 1: load z [d][t], fp8-convert, transposed+swizzled store; Sum z^2 ----
    float zsq = 0.f;
    {
        int t = lane, hf = (t >> 4) & 1;
        #pragma unroll 2
        for (int j = 0; j < 8; ++j) {
            int dgrp = w + 4 * j;
            int d0 = dgrp * 8;
            float f0 = zb[(d0 + 0) * T_ + t];
            float f1 = zb[(d0 + 1) * T_ + t];
            float f2 = zb[(d0 + 2) * T_ + t];
            float f3 = zb[(d0 + 3) * T_ + t];
            float f4 = zb[(d0 + 4) * T_ + t];
            float f5 = zb[(d0 + 5) * T_ + t];
            float f6 = zb[(d0 + 6) * T_ + t];
            float f7 = zb[(d0 + 7) * T_ + t];
            zsq += f0*f0 + f1*f1 + f2*f2 + f3*f3 + f4*f4 + f5*f5 + f6*f6 + f7*f7;
            uint32_t p0 = (uint32_t)__builtin_amdgcn_cvt_pk_fp8_f32(f0, f1, 0, false);
            p0 = (uint32_t)__builtin_amdgcn_cvt_pk_fp8_f32(f2, f3, (int)p0, true);
            uint32_t p1 = (uint32_t)__builtin_amdgcn_cvt_pk_fp8_f32(f4, f5, 0, false);
            p1 = (uint32_t)__builtin_amdgcn_cvt_pk_fp8_f32(f6, f7, (int)p1, true);
            int c = dgrp >> 1, h = dgrp & 1;
            *(uint2*)&xs[t * 256 + ((c ^ (t & 15)) << 4) + ((h ^ hf) << 3)] =
                make_uint2(p0, p1);
        }
    }

    // ---- prefetch tile j=0 (B-frags + eh) — independent of xs, hides under barrier ----
    int ct0 = w * 16;
    const char* ebL = (const char*)embf8 + (size_t)ct0 * 4096 + (size_t)lane * 16;
    longx2 qqA[4], qqB[4];
    float ehA, ehB;
    #pragma unroll
    for (int i = 0; i < 4; ++i)
        qqA[i] = *(const longx2*)(ebL + i * 1024);
    ehA = esqh[ct0 * 16 + ml];

    __syncthreads();

    // ---- Phase 2: persistent A fragments, ALL 4 point-sets per wave ----
    long afr[4][8];
    #pragma unroll
    for (int s = 0; s < 4; ++s) {
        int pnt = s * 16 + ml;
        #pragma unroll
        for (int kk = 0; kk < 8; ++kk) {
            int c = 2 * kk + (quad >> 1), h = quad & 1;
            afr[s][kk] = *(const long*)&xs[pnt * 256 + ((c ^ ml) << 4) + ((h ^ (s & 1)) << 3)];
        }
    }

    float bv[4][4];
    #pragma unroll
    for (int s = 0; s < 4; ++s)
        #pragma unroll
        for (int i = 0; i < 4; ++i) bv[s][i] = 1e30f;

    // ---- Phase 3: barrier-free k-loop, double-buffered B-frags ----
    const unsigned hi_mask = 0xFFFFFC00u;

#define VQ_PREFETCH(QQ, EH, J)                                                  \
    {                                                                           \
        const char* p_ = ebL + (size_t)(J) * 4096;                              \
        _Pragma("unroll")                                                       \
        for (int i = 0; i < 4; ++i)                                             \
            QQ[i] = *(const longx2*)(p_ + i * 1024);                            \
        EH = esqh[(ct0 + (J)) * 16 + ml];                                       \
    }

#define VQ_STEP(QQ, EH, J)                                                      \
    {                                                                           \
        floatx4 a0 = {0.f,0.f,0.f,0.f}, a1 = {0.f,0.f,0.f,0.f};                 \
        floatx4 a2 = {0.f,0.f,0.f,0.f}, a3 = {0.f,0.f,0.f,0.f};                 \
        _Pragma("unroll")                                                       \
        for (int i = 0; i < 4; ++i) {                                           \
            long bf0 = QQ[i][0], bf1 = QQ[i][1];                                \
            a0 = __builtin_amdgcn_mfma_f32_16x16x32_fp8_fp8(afr[0][2*i],   bf0, a0, 0, 0, 0); \
            a1 = __builtin_amdgcn_mfma_f32_16x16x32_fp8_fp8(afr[1][2*i],   bf0, a1, 0, 0, 0); \
            a2 = __builtin_amdgcn_mfma_f32_16x16x32_fp8_fp8(afr[2][2*i],   bf0, a2, 0, 0, 0); \
            a3 = __builtin_amdgcn_mfma_f32_16x16x32_fp8_fp8(afr[3][2*i],   bf0, a3, 0, 0, 0); \
            a0 = __builtin_amdgcn_mfma_f32_16x16x32_fp8_fp8(afr[0][2*i+1], bf1, a0, 0, 0, 0); \
            a1 = __builtin_amdgcn_mfma_f32_16x16x32_fp8_fp8(afr[1][2*i+1], bf1, a1, 0, 0, 0); \
            a2 = __builtin_amdgcn_mfma_f32_16x16x32_fp8_fp8(afr[2][2*i+1], bf1, a2, 0, 0, 0); \
            a3 = __builtin_amdgcn_mfma_f32_16x16x32_fp8_fp8(afr[3][2*i+1], bf1, a3, 0, 0, 0); \
        }                                                                       \
        unsigned cbits = (unsigned)((ct0 + (J)) * 16 + ml);                     \
        _Pragma("unroll")                                                       \
        for (int i = 0; i < 4; ++i) {                                           \
            float d0 = EH - a0[i];                                              \
            bv[0][i] = fminf(bv[0][i], __uint_as_float((__float_as_uint(d0) & hi_mask) | cbits)); \
            float d1 = EH - a1[i];                                              \
            bv[1][i] = fminf(bv[1][i], __uint_as_float((__float_as_uint(d1) & hi_mask) | cbits)); \
            float d2 = EH - a2[i];                                              \
            bv[2][i] = fminf(bv[2][i], __uint_as_float((__float_as_uint(d2) & hi_mask) | cbits)); \
            float d3 = EH - a3[i];                                              \
            bv[3][i] = fminf(bv[3][i], __uint_as_float((__float_as_uint(d3) & hi_mask) | cbits)); \
        }                                                                       \
    }

    #pragma unroll 1
    for (int j = 0; j < 16; j += 2) {
        VQ_PREFETCH(qqB, ehB, j + 1)        // tile j+1 in flight over tile j's MFMAs
        VQ_STEP(qqA, ehA, j)
        if (j + 2 < 16)
            VQ_PREFETCH(qqA, ehA, j + 2)    // tile j+2 in flight over tile j+1's MFMAs
        VQ_STEP(qqB, ehB, j + 1)
    }

#undef VQ_PREFETCH
#undef VQ_STEP

    // ---- per-wave min over the 16 code-lanes; publish packed candidates ----
    #pragma unroll
    for (int s = 0; s < 4; ++s)
        #pragma unroll
        for (int i = 0; i < 4; ++i) {
            float v = bv[s][i];
            #pragma unroll
            for (int off = 1; off < 16; off <<= 1)
                v = fminf(v, __shfl_xor(v, off, 64));
            if (ml == 0) wvals[w][s * 16 + quad * 4 + i] = v;
        }
    #pragma unroll
    for (int off = 32; off; off >>= 1) zsq += __shfl_xor(zsq, off, 64);
    if (lane == 0) zred[w] = zsq;
    __syncthreads();

    // ---- cross-wave merge (wave 0) + loss via algebra ----
    if (tid < 64) {
        int t = tid;
        float wv = fminf(fminf(wvals[0][t], wvals[1][t]),
                         fminf(wvals[2][t], wvals[3][t]));
        pidx[t] = (int)(__float_as_uint(wv) & 1023u);
        float lsum = wv;          // packed float == bv to 2^-13 relative
        #pragma unroll
        for (int off = 32; off; off >>= 1) lsum += __shfl_xor(lsum, off, 64);
        if (t == 0) {
            float tot = zred[0] + zred[1] + zred[2] + zred[3] + lsum * (2.0f / 1024.f);
            atomicAdd(lossp, tot * (1.25f / 16777216.0f));   // 1.25/(N*D)
        }
    }
    __syncthreads();

    // ---- Phase 4a: gather winning fp8 rows into xs (piece layout) ----
    #pragma unroll
    for (int m = 0; m < 4; ++m) {
        int t = (tid >> 4) + 16 * m;
        int g = tid & 15;             // chunk: piece i=g>>2, q=g&3
        int code = pidx[t];
        const char* src = (const char*)embf8 + (size_t)(code >> 4) * 4096
                        + (g >> 2) * 1024 + ((g & 3) * 16 + (code & 15)) * 16;
        uint4 v = *(const uint4*)src;
        *(uint4*)&xs[t * 256 + ((g ^ (t & 15)) << 4)] = v;
    }
    __syncthreads();

    // ---- Phase 4b: dequant + transpose-write (piece-order byte decode) ----
    float* ob = out0 + (size_t)b * (D_ * T_) + t0;
    {
        int t = lane;
        #pragma unroll
        for (int jj = 0; jj < 4; ++jj) {
            int g = w + 4 * jj;            // 16-byte chunk 0..15
            uint4 v = *(const uint4*)&xs[t * 256 + ((g ^ (t & 15)) << 4)];
            uint32_t wd[4] = {v.x, v.y, v.z, v.w};
            #pragma unroll
            for (int u = 0; u < 4; ++u) {
                int kk = (g >> 2) * 2 + (u >> 1);
                int d0 = kk * 32 + (g & 3) * 8 + (u & 1) * 4;
                floatx2 lo = __builtin_amdgcn_cvt_pk_f32_fp8((int)wd[u], false);
                floatx2 hi = __builtin_amdgcn_cvt_pk_f32_fp8((int)wd[u], true);
                ob[(d0 + 0) * T_ + t] = lo[0] * (1.f / 1024.f);
                ob[(d0 + 1) * T_ + t] = lo[1] * (1.f / 1024.f);
                ob[(d0 + 2) * T_ + t] = hi[0] * (1.f / 1024.f);
                ob[(d0 + 3) * T_ + t] = hi[1] * (1.f / 1024.f);
            }
        }
    }
}

extern "C" void kernel_launch(void* const* d_in, const int* in_sizes, int n_in,
                              void* d_out, int out_size, void* d_ws, size_t ws_size,
                              hipStream_t stream) {
    (void)in_sizes; (void)n_in; (void)out_size; (void)ws_size;
    const float* z   = (const float*)d_in[0];
    const float* emb = (const float*)d_in[1];

    uint32_t* embf8 = (uint32_t*)d_ws;                              // 256 KiB
    float*    esqh  = (float*)((char*)d_ws + (size_t)K_ * D_);      // 4 KiB

    float* out0  = (float*)d_out;
    float* lossp = out0 + (size_t)N_ * D_;

    emb_prep<<<K_ / 4, 256, 0, stream>>>(emb, embf8, esqh, lossp);
    vq_main<<<N_ / BM, 256, 0, stream>>>(z, embf8, esqh, out0, lossp);
}

// Round 4
// 133.171 us; speedup vs baseline: 1.4744x; 1.0418x over previous
//
#include <hip/hip_runtime.h>
#include <stdint.h>

// Problem constants
#define B_   16
#define D_   256
#define T_   4096
#define K_   1024
#define N_   (B_ * T_)      // 65536 points
#define BM   64             // points per block

typedef __attribute__((ext_vector_type(4))) float floatx4;
typedef __attribute__((ext_vector_type(2))) float floatx2;
typedef __attribute__((ext_vector_type(2))) long longx2;

// ---- Kernel 0: emb fp32 -> fp8 e4m3 (scaled x1024), stored in PIECE order:
// tile ct = codes [ct*16, ct*16+16), 4 KB = 4 pieces of 1 KB. Byte for
// (code c, dim d): ct=c>>4, ml=c&15, kk=d>>5, quad=(d>>3)&3, b=d&7 at
//   ct*4096 + (kk>>1)*1024 + (quad*16+ml)*16 + (kk&1)*8 + b
// -> k-loop lane L=(quad*16+ml) reads piece i at ct*4096+i*1024+L*16: each
// load covers 1 KB contiguous across the wave and lands directly in MFMA
// B-fragment registers. esqh[c] = 1024*0.5*||e_exact||^2. Also zeroes loss.
__global__ __launch_bounds__(256) void emb_prep(const float* __restrict__ emb,
                                                uint32_t* __restrict__ embf8,
                                                float* __restrict__ esqh,
                                                float* __restrict__ lossp) {
    int w = threadIdx.x >> 6, lane = threadIdx.x & 63;
    int k = blockIdx.x * 4 + w;                       // one wave per code row
    float4 v = ((const float4*)emb)[k * 64 + lane];   // d0 = lane*4
    float a0 = v.x * 1024.f, a1 = v.y * 1024.f, a2 = v.z * 1024.f, a3 = v.w * 1024.f;
    int p = __builtin_amdgcn_cvt_pk_fp8_f32(a0, a1, 0, false);
    p = __builtin_amdgcn_cvt_pk_fp8_f32(a2, a3, p, true);
    int kk = lane >> 3, quad = (lane >> 1) & 3;       // from d0 = lane*4
    int widx = (k >> 4) * 1024 + (kk >> 1) * 256 + (quad * 16 + (k & 15)) * 4
             + (kk & 1) * 2 + (lane & 1);
    embf8[widx] = (uint32_t)p;
    float ss = a0 * a0 + a1 * a1 + a2 * a2 + a3 * a3;   // exact (pre-fp8) scaled norm
    #pragma unroll
    for (int off = 32; off; off >>= 1) ss += __shfl_xor(ss, off, 64);
    if (lane == 0) esqh[k] = ss * (0.5f / 1024.f);      // = 1024 * 0.5*||e||^2
    if (blockIdx.x == 0 && threadIdx.x == 0) *lossp = 0.f;
}

// ---- Main kernel (R4: residency-4 restructure) ----
// R3 post-mortem: 148 combined regs -> 3 blocks/CU resident vs grid 4/CU
// -> TWO generations per CU (gen2 at 4 waves/CU) -> measured Occupancy ~21%
// and ~2x ideal time. Fix: shrink per-wave state so 4 blocks/CU fit.
//   Wave w: point-HALF ph=w>>1 (sets 2ph,2ph+1), code-HALF ch=w&1
//   (32 tiles). afr 64->32 regs. 4 MFMA chains kept via k-split (lo=pieces
//   0,1 / hi=pieces 2,3 per set). Combined regs ~110-122 -> (256,4), no
//   spill, 16 waves/CU, single generation. embf8 L2 traffic 2x (L2-hit,
//   FETCH_SIZE unaffected).
// eh folded into acc: P1 stores NEGATED z fp8 (VOP3 neg modifier, exact),
// chains start from C={eh,..} (lo) / 0 (hi), so d = lo[i]+hi[i] directly
// = 1024*(0.5||e||^2 - x.e). Kills the per-tile v_sub AND 12/16 init movs.
// xs swizzle (phases 1-3), byte offset of d in row t:
//   c=d>>4, h=(d>>3)&1 -> ((c ^ (t&15))<<4) + ((h ^ ((t>>4)&1))<<3) + (d&7)
// Phase 4 reuses xs with a 16B-chunk swizzle: chunk g at ((g ^ (t&15))<<4).
// Argmin state: packed float, low 10 mantissa bits = code index; v_min_f32
// compares true value to 2^-13 relative, index rides along. Ties/reorder
// flips bounded by codebook spread 2/1024 = absmax already observed.
__global__ __launch_bounds__(256, 4) void vq_main(const float* __restrict__ z,
                                                  const uint32_t* __restrict__ embf8,
                                                  const float* __restrict__ esqh,
                                                  float* __restrict__ out0,
                                                  float* __restrict__ lossp) {
    __shared__ __align__(16) unsigned char xs[BM * 256];   // 16 KiB
    __shared__ float wvals[4][BM];
    __shared__ int   pidx[BM];
    __shared__ float zred[4];

    int tid  = threadIdx.x;
    int lane = tid & 63, w = tid >> 6;
    int ml   = lane & 15, quad = lane >> 4;
    int ph   = w >> 1, ch = w & 1;
    int blk  = blockIdx.x;
    int b    = blk >> 6;
    int t0   = (blk & 63) * BM;
    const float* zb = z + (size_t)b * (D_ * T_) + t0;

    // ---- Phase 1: load z [d][t], NEGATED fp8-convert, transposed+swizzled store ----
    float zsq = 0.f;
    {
        int t = lane, hf = (t >> 4) & 1;
        #pragma unroll 2
        for (int j = 0; j < 8; ++j) {
            int dgrp = w + 4 * j;
            int d0 = dgrp * 8;
            float f0 = zb[(d0 + 0) * T_ + t];
            float f1 = zb[(d0 + 1) * T_ + t];
            float f2 = zb[(d0 + 2) * T_ + t];
            float f3 = zb[(d0 + 3) * T_ + t];
            float f4 = zb[(d0 + 4) * T_ + t];
            float f5 = zb[(d0 + 5) * T_ + t];
            float f6 = zb[(d0 + 6) * T_ + t];
            float f7 = zb[(d0 + 7) * T_ + t];
            zsq += f0*f0 + f1*f1 + f2*f2 + f3*f3 + f4*f4 + f5*f5 + f6*f6 + f7*f7;
            uint32_t p0 = (uint32_t)__builtin_amdgcn_cvt_pk_fp8_f32(-f0, -f1, 0, false);
            p0 = (uint32_t)__builtin_amdgcn_cvt_pk_fp8_f32(-f2, -f3, (int)p0, true);
            uint32_t p1 = (uint32_t)__builtin_amdgcn_cvt_pk_fp8_f32(-f4, -f5, 0, false);
            p1 = (uint32_t)__builtin_amdgcn_cvt_pk_fp8_f32(-f6, -f7, (int)p1, true);
            int c = dgrp >> 1, h = dgrp & 1;
            *(uint2*)&xs[t * 256 + ((c ^ (t & 15)) << 4) + ((h ^ hf) << 3)] =
                make_uint2(p0, p1);
        }
    }

    // ---- prefetch tile j=0 (B-frags + eh) — independent of xs, hides under barrier ----
    int ct0 = ch * 32;                        // this wave's 32-tile code half
    const char* ebL = (const char*)embf8 + (size_t)ct0 * 4096 + (size_t)lane * 16;
    longx2 qqA[4], qqB[4];
    float ehA, ehB;
    #pragma unroll
    for (int i = 0; i < 4; ++i)
        qqA[i] = *(const longx2*)(ebL + i * 1024);
    ehA = esqh[ct0 * 16 + ml];

    __syncthreads();

    // ---- Phase 2: persistent A fragments, 2 point-sets per wave ----
    long afr[2][8];
    #pragma unroll
    for (int ss = 0; ss < 2; ++ss) {
        int s = 2 * ph + ss;
        int pnt = s * 16 + ml;
        #pragma unroll
        for (int kk = 0; kk < 8; ++kk) {
            int c = 2 * kk + (quad >> 1), h = quad & 1;
            afr[ss][kk] = *(const long*)&xs[pnt * 256 + ((c ^ ml) << 4) + ((h ^ (s & 1)) << 3)];
        }
    }

    float bv[2][4];
    #pragma unroll
    for (int ss = 0; ss < 2; ++ss)
        #pragma unroll
        for (int i = 0; i < 4; ++i) bv[ss][i] = 1e30f;

    const floatx4 zv = {0.f, 0.f, 0.f, 0.f};
    const unsigned hi_mask = 0xFFFFFC00u;

#define VQ_PREFETCH(QQ, EH, J)                                                  \
    {                                                                           \
        const char* p_ = ebL + (size_t)(J) * 4096;                              \
        _Pragma("unroll")                                                       \
        for (int i = 0; i < 4; ++i)                                             \
            QQ[i] = *(const longx2*)(p_ + i * 1024);                            \
        EH = esqh[(ct0 + (J)) * 16 + ml];                                       \
    }

// 16 MFMA, 4 chains (2 sets x lo/hi k-halves), chains start from C=ehv / zv.
// A holds -x so acc = eh - x.e pieces; d = lo+hi.
#define VQ_STEP(QQ, EH, J)                                                      \
    {                                                                           \
        floatx4 ehv = {EH, EH, EH, EH};                                         \
        floatx4 lo0, lo1, hi0, hi1;                                             \
        lo0 = __builtin_amdgcn_mfma_f32_16x16x32_fp8_fp8(afr[0][0], QQ[0][0], ehv, 0, 0, 0); \
        lo1 = __builtin_amdgcn_mfma_f32_16x16x32_fp8_fp8(afr[1][0], QQ[0][0], ehv, 0, 0, 0); \
        hi0 = __builtin_amdgcn_mfma_f32_16x16x32_fp8_fp8(afr[0][4], QQ[2][0], zv,  0, 0, 0); \
        hi1 = __builtin_amdgcn_mfma_f32_16x16x32_fp8_fp8(afr[1][4], QQ[2][0], zv,  0, 0, 0); \
        lo0 = __builtin_amdgcn_mfma_f32_16x16x32_fp8_fp8(afr[0][1], QQ[0][1], lo0, 0, 0, 0); \
        lo1 = __builtin_amdgcn_mfma_f32_16x16x32_fp8_fp8(afr[1][1], QQ[0][1], lo1, 0, 0, 0); \
        hi0 = __builtin_amdgcn_mfma_f32_16x16x32_fp8_fp8(afr[0][5], QQ[2][1], hi0, 0, 0, 0); \
        hi1 = __builtin_amdgcn_mfma_f32_16x16x32_fp8_fp8(afr[1][5], QQ[2][1], hi1, 0, 0, 0); \
        lo0 = __builtin_amdgcn_mfma_f32_16x16x32_fp8_fp8(afr[0][2], QQ[1][0], lo0, 0, 0, 0); \
        lo1 = __builtin_amdgcn_mfma_f32_16x16x32_fp8_fp8(afr[1][2], QQ[1][0], lo1, 0, 0, 0); \
        hi0 = __builtin_amdgcn_mfma_f32_16x16x32_fp8_fp8(afr[0][6], QQ[3][0], hi0, 0, 0, 0); \
        hi1 = __builtin_amdgcn_mfma_f32_16x16x32_fp8_fp8(afr[1][6], QQ[3][0], hi1, 0, 0, 0); \
        lo0 = __builtin_amdgcn_mfma_f32_16x16x32_fp8_fp8(afr[0][3], QQ[1][1], lo0, 0, 0, 0); \
        lo1 = __builtin_amdgcn_mfma_f32_16x16x32_fp8_fp8(afr[1][3], QQ[1][1], lo1, 0, 0, 0); \
        hi0 = __builtin_amdgcn_mfma_f32_16x16x32_fp8_fp8(afr[0][7], QQ[3][1], hi0, 0, 0, 0); \
        hi1 = __builtin_amdgcn_mfma_f32_16x16x32_fp8_fp8(afr[1][7], QQ[3][1], hi1, 0, 0, 0); \
        unsigned cbits = (unsigned)((ct0 + (J)) * 16 + ml);                     \
        _Pragma("unroll")                                                       \
        for (int i = 0; i < 4; ++i) {                                           \
            float d0 = lo0[i] + hi0[i];                                         \
            bv[0][i] = fminf(bv[0][i], __uint_as_float((__float_as_uint(d0) & hi_mask) | cbits)); \
            float d1 = lo1[i] + hi1[i];                                         \
            bv[1][i] = fminf(bv[1][i], __uint_as_float((__float_as_uint(d1) & hi_mask) | cbits)); \
        }                                                                       \
    }

    // ---- Phase 3: barrier-free k-loop over 32 tiles, double-buffered ----
    #pragma unroll 1
    for (int j = 0; j < 32; j += 2) {
        VQ_PREFETCH(qqB, ehB, j + 1)        // tile j+1 in flight over tile j's MFMAs
        VQ_STEP(qqA, ehA, j)
        if (j + 2 < 32)
            VQ_PREFETCH(qqA, ehA, j + 2)    // tile j+2 in flight over tile j+1's MFMAs
        VQ_STEP(qqB, ehB, j + 1)
    }

#undef VQ_PREFETCH
#undef VQ_STEP

    // ---- per-wave min over the 16 code-lanes; publish packed candidates ----
    #pragma unroll
    for (int ss = 0; ss < 2; ++ss)
        #pragma unroll
        for (int i = 0; i < 4; ++i) {
            float v = bv[ss][i];
            #pragma unroll
            for (int off = 1; off < 16; off <<= 1)
                v = fminf(v, __shfl_xor(v, off, 64));
            if (ml == 0) wvals[w][(2 * ph + ss) * 16 + quad * 4 + i] = v;
        }
    #pragma unroll
    for (int off = 32; off; off >>= 1) zsq += __shfl_xor(zsq, off, 64);
    if (lane == 0) zred[w] = zsq;
    __syncthreads();

    // ---- cross-wave merge (wave 0) + loss via algebra ----
    // Point t lives in waves 2*(t>>5) and 2*(t>>5)+1 (the two code-halves).
    if (tid < 64) {
        int t = tid, qb = (t >> 5) * 2;
        float wv = fminf(wvals[qb][t], wvals[qb + 1][t]);
        pidx[t] = (int)(__float_as_uint(wv) & 1023u);
        float lsum = wv;          // packed float == bv to 2^-13 relative
        #pragma unroll
        for (int off = 32; off; off >>= 1) lsum += __shfl_xor(lsum, off, 64);
        if (t == 0) {
            float tot = zred[0] + zred[1] + zred[2] + zred[3] + lsum * (2.0f / 1024.f);
            atomicAdd(lossp, tot * (1.25f / 16777216.0f));   // 1.25/(N*D)
        }
    }
    __syncthreads();

    // ---- Phase 4a: gather winning fp8 rows into xs (piece layout) ----
    #pragma unroll
    for (int m = 0; m < 4; ++m) {
        int t = (tid >> 4) + 16 * m;
        int g = tid & 15;             // chunk: piece i=g>>2, q=g&3
        int code = pidx[t];
        const char* src = (const char*)embf8 + (size_t)(code >> 4) * 4096
                        + (g >> 2) * 1024 + ((g & 3) * 16 + (code & 15)) * 16;
        uint4 v = *(const uint4*)src;
        *(uint4*)&xs[t * 256 + ((g ^ (t & 15)) << 4)] = v;
    }
    __syncthreads();

    // ---- Phase 4b: dequant + transpose-write (piece-order byte decode) ----
    float* ob = out0 + (size_t)b * (D_ * T_) + t0;
    {
        int t = lane;
        #pragma unroll
        for (int jj = 0; jj < 4; ++jj) {
            int g = w + 4 * jj;            // 16-byte chunk 0..15
            uint4 v = *(const uint4*)&xs[t * 256 + ((g ^ (t & 15)) << 4)];
            uint32_t wd[4] = {v.x, v.y, v.z, v.w};
            #pragma unroll
            for (int u = 0; u < 4; ++u) {
                int kk = (g >> 2) * 2 + (u >> 1);
                int d0 = kk * 32 + (g & 3) * 8 + (u & 1) * 4;
                floatx2 lo = __builtin_amdgcn_cvt_pk_f32_fp8((int)wd[u], false);
                floatx2 hi = __builtin_amdgcn_cvt_pk_f32_fp8((int)wd[u], true);
                ob[(d0 + 0) * T_ + t] = lo[0] * (1.f / 1024.f);
                ob[(d0 + 1) * T_ + t] = lo[1] * (1.f / 1024.f);
                ob[(d0 + 2) * T_ + t] = hi[0] * (1.f / 1024.f);
                ob[(d0 + 3) * T_ + t] = hi[1] * (1.f / 1024.f);
            }
        }
    }
}

extern "C" void kernel_launch(void* const* d_in, const int* in_sizes, int n_in,
                              void* d_out, int out_size, void* d_ws, size_t ws_size,
                              hipStream_t stream) {
    (void)in_sizes; (void)n_in; (void)out_size; (void)ws_size;
    const float* z   = (const float*)d_in[0];
    const float* emb = (const float*)d_in[1];

    uint32_t* embf8 = (uint32_t*)d_ws;                              // 256 KiB
    float*    esqh  = (float*)((char*)d_ws + (size_t)K_ * D_);      // 4 KiB

    float* out0  = (float*)d_out;
    float* lossp = out0 + (size_t)N_ * D_;

    emb_prep<<<K_ / 4, 256, 0, stream>>>(emb, embf8, esqh, lossp);
    vq_main<<<N_ / BM, 256, 0, stream>>>(z, embf8, esqh, out0, lossp);
}